// Round 1
// baseline (264.317 us; speedup 1.0000x reference)
//
#include <hip/hip_runtime.h>
#include <math.h>

typedef int v4i __attribute__((ext_vector_type(4)));

#define DIM 4096
#define BT 128
#define KT 64

// ---------------------------------------------------------------------------
// async global->LDS 16B copy (wave-uniform base + lane*16 destination rule)
// ---------------------------------------------------------------------------
__device__ __forceinline__ void async16(const void* g, void* l) {
    __builtin_amdgcn_global_load_lds((__attribute__((address_space(1))) void*)(g),
                                     (__attribute__((address_space(3))) void*)(l),
                                     16, 0, 0);
}

// ---------------------------------------------------------------------------
// Kernel 1: narrow int32 weights in [-7,7] to int8
// ---------------------------------------------------------------------------
__global__ __launch_bounds__(256) void wconv(const int* __restrict__ w,
                                             signed char* __restrict__ w8) {
    int i = blockIdx.x * 256 + threadIdx.x;       // each handles 4 elements
    int4 v = ((const int4*)w)[i];
    char4 c;
    c.x = (signed char)v.x; c.y = (signed char)v.y;
    c.z = (signed char)v.z; c.w = (signed char)v.w;
    ((char4*)w8)[i] = c;
}

// ---------------------------------------------------------------------------
// Kernel 2: blockwise FWHT (256) rotation + per-row int4 quantization
// One 256-thread block per row. Wave w handles 256-blocks {w, w+4, w+8, w+12};
// lane holds elements idx = j*64 + lane of each 256-block.
// ---------------------------------------------------------------------------
__global__ __launch_bounds__(256) void rotquant(const float* __restrict__ x,
                                                signed char* __restrict__ q,
                                                float* __restrict__ scales) {
    const int row  = blockIdx.x;
    const int lane = threadIdx.x & 63;
    const int wave = threadIdx.x >> 6;
    const float* xr = x + (size_t)row * DIM;

    float f[4][4];   // [block][reg]
    #pragma unroll
    for (int b = 0; b < 4; ++b) {
        const int base = (wave + 4 * b) * 256;
        #pragma unroll
        for (int j = 0; j < 4; ++j) f[b][j] = xr[base + j * 64 + lane];
        // FWHT stages across lanes: distances 1..32 (bits 0..5 of idx)
        #pragma unroll
        for (int d = 1; d <= 32; d <<= 1) {
            #pragma unroll
            for (int j = 0; j < 4; ++j) {
                float p = __shfl_xor(f[b][j], d, 64);
                f[b][j] = (lane & d) ? (p - f[b][j]) : (f[b][j] + p);
            }
        }
        // distance 64 (reg bit 0) and 128 (reg bit 1), then /sqrt(256)
        float t0 = f[b][0] + f[b][1], t1 = f[b][0] - f[b][1];
        float t2 = f[b][2] + f[b][3], t3 = f[b][2] - f[b][3];
        f[b][0] = (t0 + t2) * 0.0625f;
        f[b][1] = (t1 + t3) * 0.0625f;
        f[b][2] = (t0 - t2) * 0.0625f;
        f[b][3] = (t1 - t3) * 0.0625f;
    }

    // row-wide absmax
    float m = 0.0f;
    #pragma unroll
    for (int b = 0; b < 4; ++b)
        #pragma unroll
        for (int j = 0; j < 4; ++j) m = fmaxf(m, fabsf(f[b][j]));
    #pragma unroll
    for (int d = 32; d; d >>= 1) m = fmaxf(m, __shfl_xor(m, d, 64));
    __shared__ float sm[4];
    if (lane == 0) sm[wave] = m;
    __syncthreads();
    m = fmaxf(fmaxf(sm[0], sm[1]), fmaxf(sm[2], sm[3]));

    const float s = m / 7.0f;                 // exact-match reference scale
    if (threadIdx.x == 0) scales[row] = s;

    signed char* qr = q + (size_t)row * DIM;
    #pragma unroll
    for (int b = 0; b < 4; ++b) {
        const int base = (wave + 4 * b) * 256;
        #pragma unroll
        for (int j = 0; j < 4; ++j) {
            int qi = (int)rintf(f[b][j] / s);
            qi = min(7, max(-8, qi));
            qr[base + j * 64 + lane] = (signed char)qi;
        }
    }
}

// ---------------------------------------------------------------------------
// Kernel 3: int8 GEMM  C[n,o] = sum_d q[n,d] * w[o,d], fused dequant epilogue.
// 128x128 block tile, K-step 64, 4 waves x (4x4) 16x16x64 MFMA tiles.
// LDS chunks XOR-swizzled (chunk ^= row&3) to break bank conflicts.
// ---------------------------------------------------------------------------
__global__ __launch_bounds__(256) void gemm_q8(const signed char* __restrict__ A,
                                               const signed char* __restrict__ B,
                                               const float* __restrict__ rowScale,
                                               const float* __restrict__ wscale,
                                               const float* __restrict__ bias,
                                               float* __restrict__ out) {
    __shared__ __align__(16) signed char As[BT * KT];
    __shared__ __align__(16) signed char Bs[BT * KT];

    const int bm = blockIdx.y, bn = blockIdx.x;
    const int t = threadIdx.x;
    const int lane = t & 63, wave = t >> 6;
    const int wm = (wave >> 1) * 64, wn = (wave & 1) * 64;
    const int quad = lane >> 4, mr = lane & 15;

    v4i acc[4][4] = {};

    for (int kt = 0; kt < DIM; kt += KT) {
        __syncthreads();   // all waves done reading previous tile
        #pragma unroll
        for (int h = 0; h < 2; ++h) {
            const int cidx = t + 256 * h;           // 0..511
            const int row  = cidx >> 2;             // 0..127
            const int sw   = (cidx & 3) ^ (row & 3);  // swizzled global chunk
            async16(A + (size_t)(bm * BT + row) * DIM + kt + sw * 16, &As[cidx * 16]);
            async16(B + (size_t)(bn * BT + row) * DIM + kt + sw * 16, &Bs[cidx * 16]);
        }
        __syncthreads();   // drain global_load_lds (compiler emits vmcnt(0))

        v4i a[4], b[4];
        #pragma unroll
        for (int i = 0; i < 4; ++i) {
            const int r = wm + i * 16 + mr;
            a[i] = *(const v4i*)&As[r * KT + ((quad ^ (r & 3)) * 16)];
            const int c = wn + i * 16 + mr;
            b[i] = *(const v4i*)&Bs[c * KT + ((quad ^ (c & 3)) * 16)];
        }
        #pragma unroll
        for (int i = 0; i < 4; ++i)
            #pragma unroll
            for (int j = 0; j < 4; ++j)
                acc[i][j] = __builtin_amdgcn_mfma_i32_16x16x64_i8(a[i], b[j], acc[i][j], 0, 0, 0);
    }

    // epilogue: out[n,o] = acc * sx[n] * ws[o] + bias[o]
    #pragma unroll
    for (int j = 0; j < 4; ++j) {
        const int col = bn * BT + wn + j * 16 + mr;
        const float ws = wscale[col];
        const float bs = bias[col];
        #pragma unroll
        for (int i = 0; i < 4; ++i) {
            #pragma unroll
            for (int r = 0; r < 4; ++r) {
                const int row = bm * BT + wm + i * 16 + quad * 4 + r;
                out[(size_t)row * DIM + col] =
                    ((float)acc[i][j][r] * rowScale[row]) * ws + bs;
            }
        }
    }
}

// ---------------------------------------------------------------------------
extern "C" void kernel_launch(void* const* d_in, const int* in_sizes, int n_in,
                              void* d_out, int out_size, void* d_ws, size_t ws_size,
                              hipStream_t stream) {
    const float* x      = (const float*)d_in[0];
    const int*   wint   = (const int*)d_in[1];
    const float* wscale = (const float*)d_in[2];
    const float* bias   = (const float*)d_in[3];
    float* out = (float*)d_out;

    signed char* q8 = (signed char*)d_ws;                         // 16 MB
    signed char* w8 = q8 + (size_t)DIM * DIM;                     // 16 MB
    float* sx = (float*)(w8 + (size_t)DIM * DIM);                 // 16 KB

    wconv<<<(DIM * DIM / 4) / 256, 256, 0, stream>>>(wint, w8);
    rotquant<<<DIM, 256, 0, stream>>>(x, q8, sx);
    gemm_q8<<<dim3(DIM / BT, DIM / BT), 256, 0, stream>>>(q8, w8, sx, wscale, bias, out);
}

// Round 2
// 253.373 us; speedup vs baseline: 1.0432x; 1.0432x over previous
//
#include <hip/hip_runtime.h>
#include <math.h>

typedef int v4i __attribute__((ext_vector_type(4)));

#define DIM 4096
#define BT 128
#define KT 128   // K-tile bytes (int8): 32 MFMAs per barrier, 32 K-iters

// ---------------------------------------------------------------------------
// async global->LDS 16B copy (wave-uniform base + lane*16 destination rule)
// ---------------------------------------------------------------------------
__device__ __forceinline__ void async16(const void* g, void* l) {
    __builtin_amdgcn_global_load_lds((__attribute__((address_space(1))) void*)(g),
                                     (__attribute__((address_space(3))) void*)(l),
                                     16, 0, 0);
}

// ---------------------------------------------------------------------------
// Kernel 1: narrow int32 weights in [-7,7] to int8 (HBM-bound, ~13us floor)
// ---------------------------------------------------------------------------
__global__ __launch_bounds__(256) void wconv(const int* __restrict__ w,
                                             signed char* __restrict__ w8) {
    int i = blockIdx.x * 256 + threadIdx.x;       // each handles 4 elements
    int4 v = ((const int4*)w)[i];
    char4 c;
    c.x = (signed char)v.x; c.y = (signed char)v.y;
    c.z = (signed char)v.z; c.w = (signed char)v.w;
    ((char4*)w8)[i] = c;
}

// ---------------------------------------------------------------------------
// Kernel 2: blockwise FWHT(256) rotation + per-row int4 quantization.
// One 256-thread block per row. float4 loads: lane holds elems 4*lane..4*lane+3
// of each 256-block (elem bits 0,1 = reg, bits 2..7 = lane bits 0..5).
// Butterfly order ascending by distance -> bit-identical to round-1 numerics.
// ---------------------------------------------------------------------------
__global__ __launch_bounds__(256) void rotquant(const float* __restrict__ x,
                                                signed char* __restrict__ q,
                                                float* __restrict__ scales) {
    const int row  = blockIdx.x;
    const int lane = threadIdx.x & 63;
    const int wave = threadIdx.x >> 6;
    const float4* xr4 = (const float4*)(x + (size_t)row * DIM);

    // per-lane butterfly signs for the 6 cross-lane stages (masks 1..32)
    float sgn[6];
    #pragma unroll
    for (int i = 0; i < 6; ++i) sgn[i] = (lane & (1 << i)) ? -1.0f : 1.0f;

    float f[4][4];   // [256-block][reg]
    #pragma unroll
    for (int b = 0; b < 4; ++b) {
        const int blk = wave + 4 * b;            // which 256-block of the row
        float4 v = xr4[blk * 64 + lane];
        // in-register stages: distance 1 then 2 (elem bits 0,1)
        float t0 = v.x + v.y, t1 = v.x - v.y;
        float t2 = v.z + v.w, t3 = v.z - v.w;
        f[b][0] = t0 + t2; f[b][1] = t1 + t3;
        f[b][2] = t0 - t2; f[b][3] = t1 - t3;
        // cross-lane stages: distances 4..128 -> lane-xor masks 1..32
        #pragma unroll
        for (int st = 0; st < 6; ++st) {
            const int m = 1 << st;
            #pragma unroll
            for (int j = 0; j < 4; ++j) {
                float p = __shfl_xor(f[b][j], m, 64);
                f[b][j] = fmaf(sgn[st], f[b][j], p);   // bit-clear: f+p; set: p-f
            }
        }
        #pragma unroll
        for (int j = 0; j < 4; ++j) f[b][j] *= 0.0625f;   // / sqrt(256)
    }

    // row-wide absmax
    float m = 0.0f;
    #pragma unroll
    for (int b = 0; b < 4; ++b)
        #pragma unroll
        for (int j = 0; j < 4; ++j) m = fmaxf(m, fabsf(f[b][j]));
    #pragma unroll
    for (int d = 32; d; d >>= 1) m = fmaxf(m, __shfl_xor(m, d, 64));
    __shared__ float sm[4];
    if (lane == 0) sm[wave] = m;
    __syncthreads();
    m = fmaxf(fmaxf(sm[0], sm[1]), fmaxf(sm[2], sm[3]));

    const float s = m / 7.0f;                 // exact-match reference scale
    if (threadIdx.x == 0) scales[row] = s;

    char4* qr4 = (char4*)(q + (size_t)row * DIM);
    #pragma unroll
    for (int b = 0; b < 4; ++b) {
        const int blk = wave + 4 * b;
        char4 c;
        int qi;
        qi = (int)rintf(f[b][0] / s); c.x = (signed char)min(7, max(-8, qi));
        qi = (int)rintf(f[b][1] / s); c.y = (signed char)min(7, max(-8, qi));
        qi = (int)rintf(f[b][2] / s); c.z = (signed char)min(7, max(-8, qi));
        qi = (int)rintf(f[b][3] / s); c.w = (signed char)min(7, max(-8, qi));
        qr4[blk * 64 + lane] = c;
    }
}

// ---------------------------------------------------------------------------
// Kernel 3: int8 GEMM  C[n,o] = sum_d q[n,d] * w[o,d], fused dequant epilogue.
// 128x128 block tile, K-tile 128 (32 MFMAs per barrier pair, 32 iters).
// LDS rows are 128 B (stride == 0 mod 32 banks); chunk swizzle c^(row&7)
// leaves 2-way aliasing per 16-lane phase -> conflict-free per m136.
// ---------------------------------------------------------------------------
__global__ __launch_bounds__(256) void gemm_q8(const signed char* __restrict__ A,
                                               const signed char* __restrict__ B,
                                               const float* __restrict__ rowScale,
                                               const float* __restrict__ wscale,
                                               const float* __restrict__ bias,
                                               float* __restrict__ out) {
    __shared__ __align__(16) signed char As[BT * KT];   // 16 KB
    __shared__ __align__(16) signed char Bs[BT * KT];   // 16 KB

    const int bm = blockIdx.y, bn = blockIdx.x;
    const int t = threadIdx.x;
    const int lane = t & 63, wave = t >> 6;
    const int wm = (wave >> 1) * 64, wn = (wave & 1) * 64;
    const int quad = lane >> 4, mr = lane & 15;

    v4i acc[4][4] = {};

    for (int kt = 0; kt < DIM; kt += KT) {
        __syncthreads();   // all waves done reading previous tile
        // stage 128x128B of A and B: 1024 16B-chunks each, 4 per thread
        #pragma unroll
        for (int h = 0; h < 4; ++h) {
            const int cidx = t + 256 * h;             // 0..1023
            const int row  = cidx >> 3;               // 0..127
            const int g    = (cidx & 7) ^ (row & 7);  // swizzled global chunk
            async16(A + (size_t)(bm * BT + row) * DIM + kt + g * 16, &As[cidx * 16]);
            async16(B + (size_t)(bn * BT + row) * DIM + kt + g * 16, &Bs[cidx * 16]);
        }
        __syncthreads();   // drain global_load_lds (compiler emits vmcnt(0))

        #pragma unroll
        for (int s = 0; s < 2; ++s) {
            v4i a[4], b[4];
            #pragma unroll
            for (int i = 0; i < 4; ++i) {
                const int r = wm + i * 16 + mr;
                const int c = wn + i * 16 + mr;
                const int cl = s * 4 + quad;          // logical 16B chunk in row
                a[i] = *(const v4i*)&As[r * KT + ((cl ^ (r & 7)) * 16)];
                b[i] = *(const v4i*)&Bs[c * KT + ((cl ^ (c & 7)) * 16)];
            }
            #pragma unroll
            for (int i = 0; i < 4; ++i)
                #pragma unroll
                for (int j = 0; j < 4; ++j)
                    acc[i][j] = __builtin_amdgcn_mfma_i32_16x16x64_i8(a[i], b[j], acc[i][j], 0, 0, 0);
        }
    }

    // epilogue: out[n,o] = acc * sx[n] * ws[o] + bias[o]
    #pragma unroll
    for (int j = 0; j < 4; ++j) {
        const int col = bn * BT + wn + j * 16 + mr;
        const float ws = wscale[col];
        const float bs = bias[col];
        #pragma unroll
        for (int i = 0; i < 4; ++i) {
            #pragma unroll
            for (int r = 0; r < 4; ++r) {
                const int row = bm * BT + wm + i * 16 + quad * 4 + r;
                out[(size_t)row * DIM + col] =
                    ((float)acc[i][j][r] * rowScale[row]) * ws + bs;
            }
        }
    }
}

// ---------------------------------------------------------------------------
extern "C" void kernel_launch(void* const* d_in, const int* in_sizes, int n_in,
                              void* d_out, int out_size, void* d_ws, size_t ws_size,
                              hipStream_t stream) {
    const float* x      = (const float*)d_in[0];
    const int*   wint   = (const int*)d_in[1];
    const float* wscale = (const float*)d_in[2];
    const float* bias   = (const float*)d_in[3];
    float* out = (float*)d_out;

    signed char* q8 = (signed char*)d_ws;                         // 16 MB
    signed char* w8 = q8 + (size_t)DIM * DIM;                     // 16 MB
    float* sx = (float*)(w8 + (size_t)DIM * DIM);                 // 16 KB

    wconv<<<(DIM * DIM / 4) / 256, 256, 0, stream>>>(wint, w8);
    rotquant<<<DIM, 256, 0, stream>>>(x, q8, sx);
    gemm_q8<<<dim3(DIM / BT, DIM / BT), 256, 0, stream>>>(q8, w8, sx, wscale, bias, out);
}

// Round 3
// 242.414 us; speedup vs baseline: 1.0904x; 1.0452x over previous
//
#include <hip/hip_runtime.h>
#include <math.h>

typedef int v4i  __attribute__((ext_vector_type(4)));
typedef int v16i __attribute__((ext_vector_type(16)));

#define DIM 4096
#define BT 128
#define KT 128   // K-tile bytes (int8)

// ---------------------------------------------------------------------------
// async global->LDS 16B copy (wave-uniform base + lane*16 destination rule)
// ---------------------------------------------------------------------------
__device__ __forceinline__ void async16(const void* g, void* l) {
    __builtin_amdgcn_global_load_lds((__attribute__((address_space(1))) void*)(g),
                                     (__attribute__((address_space(3))) void*)(l),
                                     16, 0, 0);
}

// ---------------------------------------------------------------------------
// Fused prep: blocks [0,4096) do FWHT(256) rotation + int4 quant of one x row;
// blocks [4096, 20480) narrow 64 int32 weights each to int8.
// Fusing overlaps the two independent memory streams in one launch.
// ---------------------------------------------------------------------------
__global__ __launch_bounds__(256) void prep(const float* __restrict__ x,
                                            const int* __restrict__ w,
                                            signed char* __restrict__ q,
                                            signed char* __restrict__ w8,
                                            float* __restrict__ scales) {
    if (blockIdx.x >= 4096) {
        // ---- weight narrowing: 1 int4 load + 1 char4 store per thread ----
        int i = (blockIdx.x - 4096) * 256 + threadIdx.x;
        int4 v = ((const int4*)w)[i];
        char4 c;
        c.x = (signed char)v.x; c.y = (signed char)v.y;
        c.z = (signed char)v.z; c.w = (signed char)v.w;
        ((char4*)w8)[i] = c;
        return;
    }
    // ---- rotquant: identical numerics to round 2 (ascending-distance FWHT) --
    const int row  = blockIdx.x;
    const int lane = threadIdx.x & 63;
    const int wave = threadIdx.x >> 6;
    const float4* xr4 = (const float4*)(x + (size_t)row * DIM);

    float sgn[6];
    #pragma unroll
    for (int i = 0; i < 6; ++i) sgn[i] = (lane & (1 << i)) ? -1.0f : 1.0f;

    float f[4][4];   // [256-block][reg]
    #pragma unroll
    for (int b = 0; b < 4; ++b) {
        const int blk = wave + 4 * b;
        float4 v = xr4[blk * 64 + lane];
        float t0 = v.x + v.y, t1 = v.x - v.y;
        float t2 = v.z + v.w, t3 = v.z - v.w;
        f[b][0] = t0 + t2; f[b][1] = t1 + t3;
        f[b][2] = t0 - t2; f[b][3] = t1 - t3;
        #pragma unroll
        for (int st = 0; st < 6; ++st) {
            const int m = 1 << st;
            #pragma unroll
            for (int j = 0; j < 4; ++j) {
                float p = __shfl_xor(f[b][j], m, 64);
                f[b][j] = fmaf(sgn[st], f[b][j], p);
            }
        }
        #pragma unroll
        for (int j = 0; j < 4; ++j) f[b][j] *= 0.0625f;   // / sqrt(256)
    }

    float m = 0.0f;
    #pragma unroll
    for (int b = 0; b < 4; ++b)
        #pragma unroll
        for (int j = 0; j < 4; ++j) m = fmaxf(m, fabsf(f[b][j]));
    #pragma unroll
    for (int d = 32; d; d >>= 1) m = fmaxf(m, __shfl_xor(m, d, 64));
    __shared__ float sm[4];
    if (lane == 0) sm[wave] = m;
    __syncthreads();
    m = fmaxf(fmaxf(sm[0], sm[1]), fmaxf(sm[2], sm[3]));

    const float s = m / 7.0f;                 // exact-match reference scale
    if (threadIdx.x == 0) scales[row] = s;

    char4* qr4 = (char4*)(q + (size_t)row * DIM);
    #pragma unroll
    for (int b = 0; b < 4; ++b) {
        const int blk = wave + 4 * b;
        char4 c;
        int qi;
        qi = (int)rintf(f[b][0] / s); c.x = (signed char)min(7, max(-8, qi));
        qi = (int)rintf(f[b][1] / s); c.y = (signed char)min(7, max(-8, qi));
        qi = (int)rintf(f[b][2] / s); c.z = (signed char)min(7, max(-8, qi));
        qi = (int)rintf(f[b][3] / s); c.w = (signed char)min(7, max(-8, qi));
        qr4[blk * 64 + lane] = c;
    }
}

// ---------------------------------------------------------------------------
// int8 GEMM  C[n,o] = sum_d q[n,d] * w[o,d], fused dequant epilogue.
// 128x128 block tile, KT=128. 4 waves x (2x2) mfma_i32_32x32x32_i8 tiles
// (half the MFMA issue slots of 16x16x64, 12% faster pipe per m55).
// Running global pointers + hoisted LDS frag pointers cut per-iter VALU.
// LDS rows 128 B, chunk swizzle c^(row&7) -> conflict-free (r2: BANK_CONF=0).
// A-frag layout: row=lane&31, k=(lane>>5)*16+byte (contiguous doubled-K,
// consistent with the verified 16x16x64 i8 layout from rounds 1-2).
// C/D: col=lane&31, row=(reg&3)+8*(reg>>2)+4*(lane>>5)  [m74/m101].
// ---------------------------------------------------------------------------
__global__ __launch_bounds__(256) void gemm_q8(const signed char* __restrict__ A,
                                               const signed char* __restrict__ B,
                                               const float* __restrict__ rowScale,
                                               const float* __restrict__ wscale,
                                               const float* __restrict__ bias,
                                               float* __restrict__ out) {
    __shared__ __align__(16) signed char As[BT * KT];   // 16 KB
    __shared__ __align__(16) signed char Bs[BT * KT];   // 16 KB

    const int bm = blockIdx.y, bn = blockIdx.x;
    const int t = threadIdx.x;
    const int lane = t & 63, wave = t >> 6;
    const int wm = (wave >> 1) * 64, wn = (wave & 1) * 64;
    const int l31 = lane & 31, lh = lane >> 5;

    // running global staging pointers (incremented by KT per iter)
    const signed char* ga[4];
    const signed char* gb[4];
    #pragma unroll
    for (int h = 0; h < 4; ++h) {
        const int cidx = t + 256 * h;             // 0..1023
        const int row  = cidx >> 3;               // 0..127
        const int g    = (cidx & 7) ^ (row & 7);  // swizzled global chunk
        ga[h] = A + (size_t)(bm * BT + row) * DIM + g * 16;
        gb[h] = B + (size_t)(bn * BT + row) * DIM + g * 16;
    }

    // loop-invariant LDS fragment pointers
    const v4i* pa[2][4];
    const v4i* pb[2][4];
    #pragma unroll
    for (int i = 0; i < 2; ++i)
        #pragma unroll
        for (int s = 0; s < 4; ++s) {
            const int r  = wm + i * 32 + l31;
            const int c  = wn + i * 32 + l31;
            const int cl = 2 * s + lh;            // logical 16B chunk (k-step s)
            pa[i][s] = (const v4i*)&As[r * KT + ((cl ^ (r & 7)) * 16)];
            pb[i][s] = (const v4i*)&Bs[c * KT + ((cl ^ (c & 7)) * 16)];
        }

    v16i acc[2][2] = {};

    for (int kt = 0; kt < DIM; kt += KT) {
        __syncthreads();   // all waves done reading previous tile
        #pragma unroll
        for (int h = 0; h < 4; ++h) {
            const int l = (t + 256 * h) * 16;
            async16(ga[h], &As[l]); ga[h] += KT;
            async16(gb[h], &Bs[l]); gb[h] += KT;
        }
        __syncthreads();   // drain global_load_lds

        #pragma unroll
        for (int s = 0; s < 4; ++s) {
            const v4i a0 = *pa[0][s], a1 = *pa[1][s];
            const v4i b0 = *pb[0][s], b1 = *pb[1][s];
            acc[0][0] = __builtin_amdgcn_mfma_i32_32x32x32_i8(a0, b0, acc[0][0], 0, 0, 0);
            acc[0][1] = __builtin_amdgcn_mfma_i32_32x32x32_i8(a0, b1, acc[0][1], 0, 0, 0);
            acc[1][0] = __builtin_amdgcn_mfma_i32_32x32x32_i8(a1, b0, acc[1][0], 0, 0, 0);
            acc[1][1] = __builtin_amdgcn_mfma_i32_32x32x32_i8(a1, b1, acc[1][1], 0, 0, 0);
        }
    }

    // epilogue: out[n,o] = acc * sx[n] * ws[o] + bias[o]  (same fp expression)
    #pragma unroll
    for (int j = 0; j < 2; ++j) {
        const int col = bn * BT + wn + j * 32 + l31;
        const float ws = wscale[col];
        const float bs = bias[col];
        #pragma unroll
        for (int i = 0; i < 2; ++i) {
            const int rb = bm * BT + wm + i * 32 + 4 * lh;
            #pragma unroll
            for (int r = 0; r < 16; ++r) {
                const int row = rb + (r & 3) + 8 * (r >> 2);
                out[(size_t)row * DIM + col] =
                    ((float)acc[i][j][r] * rowScale[row]) * ws + bs;
            }
        }
    }
}

// ---------------------------------------------------------------------------
extern "C" void kernel_launch(void* const* d_in, const int* in_sizes, int n_in,
                              void* d_out, int out_size, void* d_ws, size_t ws_size,
                              hipStream_t stream) {
    const float* x      = (const float*)d_in[0];
    const int*   wint   = (const int*)d_in[1];
    const float* wscale = (const float*)d_in[2];
    const float* bias   = (const float*)d_in[3];
    float* out = (float*)d_out;

    signed char* q8 = (signed char*)d_ws;                         // 16 MB
    signed char* w8 = q8 + (size_t)DIM * DIM;                     // 16 MB
    float* sx = (float*)(w8 + (size_t)DIM * DIM);                 // 16 KB

    prep<<<4096 + 16384, 256, 0, stream>>>(x, wint, q8, w8, sx);
    gemm_q8<<<dim3(DIM / BT, DIM / BT), 256, 0, stream>>>(q8, w8, sx, wscale, bias, out);
}

// Round 4
// 235.031 us; speedup vs baseline: 1.1246x; 1.0314x over previous
//
#include <hip/hip_runtime.h>
#include <math.h>

typedef int v4i  __attribute__((ext_vector_type(4)));
typedef int v16i __attribute__((ext_vector_type(16)));

#define DIM 4096
#define BT 128
#define KT 128          // K-tile bytes (int8)
#define TILE (BT * KT)  // 16384 B per A/B tile

// ---------------------------------------------------------------------------
// async global->LDS 16B copy (wave-uniform base + lane*16 destination rule)
// ---------------------------------------------------------------------------
__device__ __forceinline__ void async16(const void* g, void* l) {
    __builtin_amdgcn_global_load_lds((__attribute__((address_space(1))) void*)(g),
                                     (__attribute__((address_space(3))) void*)(l),
                                     16, 0, 0);
}

// ---------------------------------------------------------------------------
// Fused prep (unchanged from round 3): blocks [0,4096) FWHT(256)+int4 quant;
// blocks [4096,20480) narrow int32 weights to int8.
// ---------------------------------------------------------------------------
__global__ __launch_bounds__(256) void prep(const float* __restrict__ x,
                                            const int* __restrict__ w,
                                            signed char* __restrict__ q,
                                            signed char* __restrict__ w8,
                                            float* __restrict__ scales) {
    if (blockIdx.x >= 4096) {
        int i = (blockIdx.x - 4096) * 256 + threadIdx.x;
        int4 v = ((const int4*)w)[i];
        char4 c;
        c.x = (signed char)v.x; c.y = (signed char)v.y;
        c.z = (signed char)v.z; c.w = (signed char)v.w;
        ((char4*)w8)[i] = c;
        return;
    }
    const int row  = blockIdx.x;
    const int lane = threadIdx.x & 63;
    const int wave = threadIdx.x >> 6;
    const float4* xr4 = (const float4*)(x + (size_t)row * DIM);

    float sgn[6];
    #pragma unroll
    for (int i = 0; i < 6; ++i) sgn[i] = (lane & (1 << i)) ? -1.0f : 1.0f;

    float f[4][4];
    #pragma unroll
    for (int b = 0; b < 4; ++b) {
        const int blk = wave + 4 * b;
        float4 v = xr4[blk * 64 + lane];
        float t0 = v.x + v.y, t1 = v.x - v.y;
        float t2 = v.z + v.w, t3 = v.z - v.w;
        f[b][0] = t0 + t2; f[b][1] = t1 + t3;
        f[b][2] = t0 - t2; f[b][3] = t1 - t3;
        #pragma unroll
        for (int st = 0; st < 6; ++st) {
            const int m = 1 << st;
            #pragma unroll
            for (int j = 0; j < 4; ++j) {
                float p = __shfl_xor(f[b][j], m, 64);
                f[b][j] = fmaf(sgn[st], f[b][j], p);
            }
        }
        #pragma unroll
        for (int j = 0; j < 4; ++j) f[b][j] *= 0.0625f;   // / sqrt(256)
    }

    float m = 0.0f;
    #pragma unroll
    for (int b = 0; b < 4; ++b)
        #pragma unroll
        for (int j = 0; j < 4; ++j) m = fmaxf(m, fabsf(f[b][j]));
    #pragma unroll
    for (int d = 32; d; d >>= 1) m = fmaxf(m, __shfl_xor(m, d, 64));
    __shared__ float sm[4];
    if (lane == 0) sm[wave] = m;
    __syncthreads();
    m = fmaxf(fmaxf(sm[0], sm[1]), fmaxf(sm[2], sm[3]));

    const float s = m / 7.0f;                 // exact-match reference scale
    if (threadIdx.x == 0) scales[row] = s;

    char4* qr4 = (char4*)(q + (size_t)row * DIM);
    #pragma unroll
    for (int b = 0; b < 4; ++b) {
        const int blk = wave + 4 * b;
        char4 c;
        int qi;
        qi = (int)rintf(f[b][0] / s); c.x = (signed char)min(7, max(-8, qi));
        qi = (int)rintf(f[b][1] / s); c.y = (signed char)min(7, max(-8, qi));
        qi = (int)rintf(f[b][2] / s); c.z = (signed char)min(7, max(-8, qi));
        qi = (int)rintf(f[b][3] / s); c.w = (signed char)min(7, max(-8, qi));
        qr4[blk * 64 + lane] = c;
    }
}

// ---------------------------------------------------------------------------
// int8 GEMM, double-buffered LDS software pipeline.
// Per K-tile: ONE barrier, ordered  barrier -> stage(next, other buf) ->
// compute(this buf). The compiler's vmcnt(0)-before-s_barrier then drains a
// DMA issued one full compute-block earlier (~430 cyc of MFMA+ds_read) ->
// drain is nearly free, unlike the 2-barrier structure (31% MfmaUtil, R3).
// S layout: [A0 | B0 | A1 | B1], 16 KB each (64 KB total, 2 blocks/CU).
// ---------------------------------------------------------------------------
__global__ __launch_bounds__(256) void gemm_q8(const signed char* __restrict__ A,
                                               const signed char* __restrict__ B,
                                               const float* __restrict__ rowScale,
                                               const float* __restrict__ wscale,
                                               const float* __restrict__ bias,
                                               float* __restrict__ out) {
    __shared__ __align__(16) signed char S[4 * TILE];   // 64 KB

    const int bm = blockIdx.y, bn = blockIdx.x;
    const int t = threadIdx.x;
    const int lane = t & 63, wave = t >> 6;
    const int wm = (wave >> 1) * 64, wn = (wave & 1) * 64;
    const int l31 = lane & 31, lh = lane >> 5;

    // running global staging pointers (advance KT per staged tile)
    const signed char* ga[4];
    const signed char* gb[4];
    #pragma unroll
    for (int h = 0; h < 4; ++h) {
        const int cidx = t + 256 * h;             // 0..1023
        const int row  = cidx >> 3;               // 0..127
        const int g    = (cidx & 7) ^ (row & 7);  // swizzled global chunk
        ga[h] = A + (size_t)(bm * BT + row) * DIM + g * 16;
        gb[h] = B + (size_t)(bn * BT + row) * DIM + g * 16;
    }

    // loop-invariant per-lane LDS byte offsets (buffer selected by imm const)
    int offA[2][4], offB[2][4];
    #pragma unroll
    for (int i = 0; i < 2; ++i)
        #pragma unroll
        for (int s = 0; s < 4; ++s) {
            const int r  = wm + i * 32 + l31;
            const int c  = wn + i * 32 + l31;
            const int cl = 2 * s + lh;            // logical 16B chunk (k-step s)
            offA[i][s] = r * KT + ((cl ^ (r & 7)) * 16);
            offB[i][s] = c * KT + ((cl ^ (c & 7)) * 16) + TILE;
        }

    v16i acc[2][2] = {};

#define STAGE(P) do {                                                          \
        _Pragma("unroll")                                                      \
        for (int h = 0; h < 4; ++h) {                                          \
            const int l = (P) * 2 * TILE + (t + 256 * h) * 16;                 \
            async16(ga[h], &S[l]);        ga[h] += KT;                         \
            async16(gb[h], &S[l + TILE]); gb[h] += KT;                         \
        }                                                                      \
    } while (0)

#define COMPUTE(P) do {                                                        \
        _Pragma("unroll")                                                      \
        for (int s = 0; s < 4; ++s) {                                          \
            const v4i a0 = *(const v4i*)&S[(P) * 2 * TILE + offA[0][s]];       \
            const v4i a1 = *(const v4i*)&S[(P) * 2 * TILE + offA[1][s]];       \
            const v4i b0 = *(const v4i*)&S[(P) * 2 * TILE + offB[0][s]];       \
            const v4i b1 = *(const v4i*)&S[(P) * 2 * TILE + offB[1][s]];       \
            acc[0][0] = __builtin_amdgcn_mfma_i32_32x32x32_i8(a0, b0, acc[0][0], 0, 0, 0); \
            acc[0][1] = __builtin_amdgcn_mfma_i32_32x32x32_i8(a0, b1, acc[0][1], 0, 0, 0); \
            acc[1][0] = __builtin_amdgcn_mfma_i32_32x32x32_i8(a1, b0, acc[1][0], 0, 0, 0); \
            acc[1][1] = __builtin_amdgcn_mfma_i32_32x32x32_i8(a1, b1, acc[1][1], 0, 0, 0); \
        }                                                                      \
    } while (0)

    // 32 K-tiles: stage #n -> buffer n&1; compute tile n from buffer n&1.
    STAGE(0);                                  // tile 0 -> buf0
    #pragma unroll 1
    for (int it = 0; it < 15; ++it) {
        __syncthreads(); STAGE(1); COMPUTE(0); // drain 2it,   stage 2it+1, compute 2it
        __syncthreads(); STAGE(0); COMPUTE(1); // drain 2it+1, stage 2it+2, compute 2it+1
    }
    __syncthreads(); STAGE(1); COMPUTE(0);     // tile 30 compute, tile 31 stage
    __syncthreads();           COMPUTE(1);     // tile 31 compute

#undef STAGE
#undef COMPUTE

    // epilogue: out[n,o] = acc * sx[n] * ws[o] + bias[o]
    // C/D: col = lane&31, row = (reg&3) + 8*(reg>>2) + 4*(lane>>5)  [m74/m101]
    #pragma unroll
    for (int j = 0; j < 2; ++j) {
        const int col = bn * BT + wn + j * 32 + l31;
        const float ws = wscale[col];
        const float bs = bias[col];
        #pragma unroll
        for (int i = 0; i < 2; ++i) {
            const int rb = bm * BT + wm + i * 32 + 4 * lh;
            #pragma unroll
            for (int r = 0; r < 16; ++r) {
                const int row = rb + (r & 3) + 8 * (r >> 2);
                out[(size_t)row * DIM + col] =
                    ((float)acc[i][j][r] * rowScale[row]) * ws + bs;
            }
        }
    }
}

// ---------------------------------------------------------------------------
extern "C" void kernel_launch(void* const* d_in, const int* in_sizes, int n_in,
                              void* d_out, int out_size, void* d_ws, size_t ws_size,
                              hipStream_t stream) {
    const float* x      = (const float*)d_in[0];
    const int*   wint   = (const int*)d_in[1];
    const float* wscale = (const float*)d_in[2];
    const float* bias   = (const float*)d_in[3];
    float* out = (float*)d_out;

    signed char* q8 = (signed char*)d_ws;                         // 16 MB
    signed char* w8 = q8 + (size_t)DIM * DIM;                     // 16 MB
    float* sx = (float*)(w8 + (size_t)DIM * DIM);                 // 16 KB

    prep<<<4096 + 16384, 256, 0, stream>>>(x, wint, q8, w8, sx);
    gemm_q8<<<dim3(DIM / BT, DIM / BT), 256, 0, stream>>>(q8, w8, sx, wscale, bias, out);
}